// Round 10
// baseline (572.318 us; speedup 1.0000x reference)
//
#include <hip/hip_runtime.h>

#define N_NODES 100000
#define F_IN 128
#define HID 256
#define NCLS 64
#define N_EDGES 1600000

typedef _Float16 f16;
typedef f16 half8 __attribute__((ext_vector_type(8)));
typedef f16 half4 __attribute__((ext_vector_type(4)));
typedef float f32x4 __attribute__((ext_vector_type(4)));
typedef unsigned long long u64;
typedef unsigned short u16;
typedef unsigned int u32;

// ---------------------------------------------------------------------------
// R10 CSR build: u32 count atomics sharded 8-way (cnt8[j][node], j=bid&7).
// R7/R9 pmc: u64 atomic pass flat at ~92us, VALUBusy 2%, HBM 15%; 4-deep
// in-flight null -> not issue-limited; suspect per-line RMW serialization
// (128 ops/line) + u64 width. Sharding: 32 ops/line, u32. Weighted degree
// moved out of the atomic: computed post-placement by segment-summing csr
// (k_deg), then csr weights normalized in k_normw. Correctness is shard-
// value-agnostic: seq records (j,slot); pos = segstart + sliceoff[d][j] +
// slot is unique for ANY stable per-block j.
// ---------------------------------------------------------------------------
__global__ void k_init(u32* __restrict__ cnt8, int n8) {
    int i = blockIdx.x * 256 + threadIdx.x;
    if (i < n8) cnt8[i] = 0u;
}

#define EB4  1563    // ceil(N_EDGES/1024)
#define XB   12500   // N_NODES*F_IN/4/256
#define W0B  128     // F_IN*HID/256
#define W1B  256     // HID*HID/256
#define W2B  64      // HID*NCLS/256
__global__ __launch_bounds__(256) void mega1(
        const int* __restrict__ dst,
        u32* __restrict__ cnt8, u16* __restrict__ seq,
        const float* __restrict__ x, f16* __restrict__ xh,
        const float* __restrict__ W0, f16* __restrict__ Wt0,
        const float* __restrict__ W1, f16* __restrict__ Wt1,
        const float* __restrict__ W2, f16* __restrict__ Wt2) {
    int bid = blockIdx.x;
    int t = threadIdx.x;
    if (bid < EB4) {
        const int j = bid & 7;                     // shard (any stable value ok)
        u32* myc = cnt8 + (size_t)j * N_NODES;
        int base = bid * 1024 + t;
        int d[4]; u32 old[4]; bool ok[4];
        #pragma unroll
        for (int u = 0; u < 4; ++u) {
            int i = base + u * 256;
            ok[u] = (i < N_EDGES);
            if (ok[u]) d[u] = dst[i];
        }
        #pragma unroll
        for (int u = 0; u < 4; ++u)
            if (ok[u]) old[u] = atomicAdd(&myc[d[u]], 1u);
        #pragma unroll
        for (int u = 0; u < 4; ++u)
            if (ok[u]) seq[base + u * 256] = (u16)((j << 12) | old[u]);
    } else if (bid < EB4 + XB) {
        int i = (bid - EB4) * 256 + t;       // float4 index over x
        if (i < N_NODES * (F_IN / 4)) {
            float4 v = *(const float4*)&x[(size_t)i * 4];
            half4 o;
            o[0] = (f16)v.x; o[1] = (f16)v.y; o[2] = (f16)v.z; o[3] = (f16)v.w;
            *(half4*)&xh[(size_t)i * 4] = o;
        }
    } else if (bid < EB4 + XB + W0B) {
        int i = (bid - EB4 - XB) * 256 + t;  // W0[F_IN][HID] -> Wt0[HID][F_IN]
        int k = i / HID, dd = i % HID;
        Wt0[dd * F_IN + k] = (f16)W0[i];
    } else if (bid < EB4 + XB + W0B + W1B) {
        int i = (bid - EB4 - XB - W0B) * 256 + t;
        int k = i / HID, dd = i % HID;
        Wt1[dd * HID + k] = (f16)W1[i];
    } else {
        int i = (bid - EB4 - XB - W0B - W1B) * 256 + t;
        int k = i / NCLS, dd = i % NCLS;     // W2[HID][NCLS] -> Wt2[NCLS][HID]
        Wt2[dd * HID + k] = (f16)W2[i];
    }
}

// Per-node: total cnt from 8 shards + per-shard exclusive offsets (sliceoff,
// node-major u16[8]) + within-block inclusive scan of cnt -> incl, bsum.
__global__ void k_scan1(const u32* __restrict__ cnt8,
                        int* __restrict__ cnt, u16* __restrict__ sliceoff,
                        int* __restrict__ incl, int* __restrict__ bsum, int n) {
    __shared__ int s[256];
    int t = threadIdx.x;
    int i = blockIdx.x * 256 + t;
    int v = 0;
    if (i < n) {
        u32 off = 0;
        u16 so[8];
        #pragma unroll
        for (int j = 0; j < 8; ++j) {
            u32 c = cnt8[(size_t)j * N_NODES + i];
            so[j] = (u16)off;
            off += c;
        }
        v = (int)off;
        cnt[i] = v;
        uint4 p;
        p.x = (u32)so[0] | ((u32)so[1] << 16);
        p.y = (u32)so[2] | ((u32)so[3] << 16);
        p.z = (u32)so[4] | ((u32)so[5] << 16);
        p.w = (u32)so[6] | ((u32)so[7] << 16);
        *(uint4*)&sliceoff[(size_t)i * 8] = p;
    }
    s[t] = v;
    __syncthreads();
    #pragma unroll
    for (int off = 1; off < 256; off <<= 1) {
        int x = (t >= off) ? s[t - off] : 0;
        __syncthreads();
        s[t] += x;
        __syncthreads();
    }
    if (i < n) incl[i] = s[t];
    if (t == 255) bsum[blockIdx.x] = s[255];
}

__global__ void k_scan2(const int* __restrict__ bsum, int* __restrict__ boff, int nb) {
    __shared__ int s[512];
    int t = threadIdx.x;
    int v = (t < nb) ? bsum[t] : 0;
    s[t] = v;
    __syncthreads();
    #pragma unroll
    for (int off = 1; off < 512; off <<= 1) {
        int x = (t >= off) ? s[t - off] : 0;
        __syncthreads();
        s[t] += x;
        __syncthreads();
    }
    if (t < nb) boff[t] = s[t] - v;
}

// atomic-free placement of RAW weights: pos = segstart(d) + sliceoff[d][j] + slot
__global__ void k_place(const int* __restrict__ src, const int* __restrict__ dst,
                        const float* __restrict__ w, const u16* __restrict__ seq,
                        const int* __restrict__ incl, const int* __restrict__ cnt,
                        const int* __restrict__ boff, const u16* __restrict__ sliceoff,
                        int2* __restrict__ csr, int e) {
    int i = blockIdx.x * 256 + threadIdx.x;
    if (i < e) {
        int s = src[i], d = dst[i];
        u16 sq = seq[i];
        int j = sq >> 12, slot = sq & 0xFFF;
        int pos = incl[d] - cnt[d] + boff[d >> 8] + (int)sliceoff[(size_t)d * 8 + j] + slot;
        csr[pos] = make_int2(s, __float_as_int(w[i]));
    }
}

// deg[d] = 1 (self-loop) + sum of raw w over d's csr segment -> dis, selfnorm
__global__ void k_deg(const int2* __restrict__ csr,
                      const int* __restrict__ incl, const int* __restrict__ cnt,
                      const int* __restrict__ boff,
                      float* __restrict__ dis, float* __restrict__ selfnorm, int n) {
    int i = blockIdx.x * 256 + threadIdx.x;
    if (i < n) {
        int c = cnt[i];
        int end = incl[i] + boff[i >> 8];
        float deg = 1.0f;
        for (int e = end - c; e < end; ++e)
            deg += __int_as_float(csr[e].y);
        float d = rsqrtf(deg);
        dis[i] = d;
        selfnorm[i] = d * d;
    }
}

// csr[e].y = dis[src] * w * dis[d]  (dis = 400KB, L2-resident random reads)
__global__ void k_normw(int2* __restrict__ csr,
                        const int* __restrict__ incl, const int* __restrict__ cnt,
                        const int* __restrict__ boff,
                        const float* __restrict__ dis, int n) {
    int i = blockIdx.x * 256 + threadIdx.x;
    if (i < n) {
        int c = cnt[i];
        int end = incl[i] + boff[i >> 8];
        float dd = dis[i];
        for (int e = end - c; e < end; ++e) {
            int2 en = csr[e];
            float nw = dis[en.x] * __int_as_float(en.y) * dd;
            csr[e] = make_int2(en.x, __float_as_int(nw));
        }
    }
}

// ---------------------------------------------------------------------------
// MFMA GEMM: out[n, c] = sum_k in[n, k] * W[k, c]  (+bias, relu if BIAS_RELU)
// Block tile 128x64, 4 waves. VGPR-staging body (verified); 1D grid +
// bijective XCD-chunk swizzle. global_load_lds variant suspect in container
// failures -- not reintroduced. agg-GEMM fusion structurally dead (R5/R6).
// ---------------------------------------------------------------------------
template <int K, int DOUT, bool BIAS_RELU>
__global__ __launch_bounds__(256) void gemm_mfma(const f16* __restrict__ in,
                                                 const f16* __restrict__ Wt,  // [DOUT][K]
                                                 const float* __restrict__ bias,
                                                 f16* __restrict__ out,
                                                 int nNodes) {
    constexpr int BM = 128, BN = 64, BK = 32;
    constexpr int NB = DOUT / BN;
    constexpr int AP = 40;
    constexpr int CP = 72;
    constexpr int SMEM = (BM * AP + BN * AP) > (BM * CP) ? (BM * AP + BN * AP) : (BM * CP);
    __shared__ f16 smem[SMEM];
    f16* As = smem;
    f16* Bs = smem + BM * AP;

    const int nwg = gridDim.x;
    const int b = blockIdx.x;
    const int q = nwg >> 3, r = nwg & 7, xcd = b & 7;
    const int wk = (xcd < r ? xcd * (q + 1) : r * (q + 1) + (xcd - r) * q) + (b >> 3);
    const int bx = wk / NB, by = wk % NB;

    const int t = threadIdx.x;
    const int w = t >> 6;
    const int lane = t & 63;
    const int quad = lane >> 4;
    const int l16 = lane & 15;
    const int nodeBase = bx * BM;
    const int colBase = by * BN;

    f32x4 acc[2][4] = {};

    for (int k0 = 0; k0 < K; k0 += BK) {
        {
            int koff = (t & 3) * 8;
            #pragma unroll
            for (int p = 0; p < 2; ++p) {
                int r2 = (t >> 2) + p * 64;
                int gn = nodeBase + r2;
                if (gn >= nNodes) gn = nNodes - 1;
                half8 v = *(const half8*)&in[(size_t)gn * K + k0 + koff];
                *(half8*)&As[r2 * AP + koff] = v;
            }
        }
        {
            int koff = (t & 3) * 8;
            int c = t >> 2;
            half8 v = *(const half8*)&Wt[(size_t)(colBase + c) * K + k0 + koff];
            *(half8*)&Bs[c * AP + koff] = v;
        }
        __syncthreads();

        half8 a[2];
        #pragma unroll
        for (int rt = 0; rt < 2; ++rt)
            a[rt] = *(const half8*)&As[(w * 32 + rt * 16 + l16) * AP + quad * 8];
        #pragma unroll
        for (int ct = 0; ct < 4; ++ct) {
            half8 bf = *(const half8*)&Bs[(ct * 16 + l16) * AP + quad * 8];
            acc[0][ct] = __builtin_amdgcn_mfma_f32_16x16x32_f16(a[0], bf, acc[0][ct], 0, 0, 0);
            acc[1][ct] = __builtin_amdgcn_mfma_f32_16x16x32_f16(a[1], bf, acc[1][ct], 0, 0, 0);
        }
        __syncthreads();
    }

    float bv[4];
    #pragma unroll
    for (int ct = 0; ct < 4; ++ct)
        bv[ct] = BIAS_RELU ? bias[colBase + ct * 16 + l16] : 0.0f;

    f16* Cs = smem;
    #pragma unroll
    for (int rt = 0; rt < 2; ++rt)
        #pragma unroll
        for (int ct = 0; ct < 4; ++ct)
            #pragma unroll
            for (int rr2 = 0; rr2 < 4; ++rr2) {
                int rr = w * 32 + rt * 16 + quad * 4 + rr2;
                int cc = ct * 16 + l16;
                float v = acc[rt][ct][rr2];
                if (BIAS_RELU) v = fmaxf(v + bv[ct], 0.0f);
                Cs[rr * CP + cc] = (f16)v;
            }
    __syncthreads();
    #pragma unroll
    for (int p = 0; p < 4; ++p) {
        int rr = (t >> 3) + p * 32;
        int gn = nodeBase + rr;
        int chunk = (t & 7) * 8;
        if (gn < nNodes)
            *(half8*)&out[(size_t)gn * DOUT + colBase + chunk] =
                *(const half8*)&Cs[rr * CP + chunk];
    }
}

// ---------------------------------------------------------------------------
// CSR aggregation: out[d,:] = sn[d]*h[d,:] (+bias) + sum_e w_e*h[src_e,:]
// Unroll-2 (R4: unroll-4 null; gather BW-bound at ~3.8 TB/s pattern ceiling,
// FETCH at the 8-XCD compulsory floor). Split dispatches for visibility.
// ---------------------------------------------------------------------------
template <int DOUT, int TPN, bool HAS_BIAS, bool OUT_F32>
__global__ __launch_bounds__(256) void agg_csr(const f16* __restrict__ h,
                                               const int2* __restrict__ csr,
                                               const int* __restrict__ incl,
                                               const int* __restrict__ cnt,
                                               const int* __restrict__ boff,
                                               const float* __restrict__ sn,
                                               const float* __restrict__ bias,
                                               void* __restrict__ outv,
                                               int nodeBase, int nodeEnd) {
    constexpr int NPB = 256 / TPN;
    int node = nodeBase + blockIdx.x * NPB + threadIdx.x / TPN;
    if (node >= nodeEnd) return;
    int lane = threadIdx.x % TPN;
    int col = lane * 8;

    float s = sn[node];
    half8 hv = *(const half8*)&h[(size_t)node * DOUT + col];
    float acc[8];
    #pragma unroll
    for (int i = 0; i < 8; ++i)
        acc[i] = s * (float)hv[i] + (HAS_BIAS ? bias[col + i] : 0.0f);

    int c = cnt[node];
    int end = incl[node] + boff[node >> 8];
    int e = end - c;

    for (; e + 1 < end; e += 2) {
        int2 e0 = csr[e], e1 = csr[e + 1];
        float w0 = __int_as_float(e0.y), w1 = __int_as_float(e1.y);
        half8 a0 = *(const half8*)&h[(size_t)e0.x * DOUT + col];
        half8 a1 = *(const half8*)&h[(size_t)e1.x * DOUT + col];
        #pragma unroll
        for (int i = 0; i < 8; ++i) acc[i] += w0 * (float)a0[i] + w1 * (float)a1[i];
    }
    if (e < end) {
        int2 e0 = csr[e];
        float w0 = __int_as_float(e0.y);
        half8 a0 = *(const half8*)&h[(size_t)e0.x * DOUT + col];
        #pragma unroll
        for (int i = 0; i < 8; ++i) acc[i] += w0 * (float)a0[i];
    }

    if (OUT_F32) {
        float* out = (float*)outv;
        float4 r0 = make_float4(acc[0], acc[1], acc[2], acc[3]);
        float4 r1 = make_float4(acc[4], acc[5], acc[6], acc[7]);
        *(float4*)&out[(size_t)node * DOUT + col] = r0;
        *(float4*)&out[(size_t)node * DOUT + col + 4] = r1;
    } else {
        f16* out = (f16*)outv;
        half8 o;
        #pragma unroll
        for (int i = 0; i < 8; ++i) o[i] = (f16)acc[i];
        *(half8*)&out[(size_t)node * DOUT + col] = o;
    }
}

// ---------------------------------------------------------------------------
extern "C" void kernel_launch(void* const* d_in, const int* in_sizes, int n_in,
                              void* d_out, int out_size, void* d_ws, size_t ws_size,
                              hipStream_t stream) {
    const float* x  = (const float*)d_in[0];
    const int*   ei = (const int*)d_in[1];
    const float* ew = (const float*)d_in[2];
    const float* W0 = (const float*)d_in[3];
    const float* b0 = (const float*)d_in[4];
    const float* W1 = (const float*)d_in[5];
    const float* b1 = (const float*)d_in[6];
    const float* W2 = (const float*)d_in[7];
    const float* b2 = (const float*)d_in[8];
    const int* src = ei;
    const int* dst = ei + N_EDGES;
    float* outp = (float*)d_out;

    // workspace carve-up (8B-aligned first)
    char* ws = (char*)d_ws;
    u32*   cnt8     = (u32*)ws;    ws += (size_t)8 * N_NODES * 4;   // 3.2MB
    int2*  csr      = (int2*)ws;   ws += (size_t)N_EDGES * 8;
    u16*   seq      = (u16*)ws;    ws += (size_t)N_EDGES * 4;       // u16 used
    u16*   sliceoff = (u16*)ws;    ws += (size_t)N_NODES * 8 * 2;   // 1.6MB
    float* dis      = (float*)ws;  ws += N_NODES * 4;
    float* selfnorm = (float*)ws;  ws += N_NODES * 4;
    int*   cnt      = (int*)ws;    ws += N_NODES * 4;
    int*   incl     = (int*)ws;    ws += N_NODES * 4;
    int*   bsum     = (int*)ws;    ws += 512 * 4;
    int*   boff     = (int*)ws;    ws += 512 * 4;
    f16*   xh       = (f16*)ws;    ws += (size_t)N_NODES * F_IN * 2;
    f16*   Wt0      = (f16*)ws;    ws += F_IN * HID * 2;
    f16*   Wt1      = (f16*)ws;    ws += HID * HID * 2;
    f16*   Wt2      = (f16*)ws;    ws += HID * NCLS * 2;
    f16*   bufA     = (f16*)ws;    ws += (size_t)N_NODES * HID * 2;
    f16*   bufB     = (f16*)ws;    ws += (size_t)N_NODES * HID * 2;

    const int nb = (N_NODES + 255) / 256;   // 391
    const int eb = (N_EDGES + 255) / 256;   // 6250

    // ---- CSR build + norm ----
    k_init<<<(8 * N_NODES + 255) / 256, 256, 0, stream>>>(cnt8, 8 * N_NODES);
    mega1<<<EB4 + XB + W0B + W1B + W2B, 256, 0, stream>>>(
        dst, cnt8, seq, x, xh, W0, Wt0, W1, Wt1, W2, Wt2);
    k_scan1<<<nb, 256, 0, stream>>>(cnt8, cnt, sliceoff, incl, bsum, N_NODES);
    k_scan2<<<1, 512, 0, stream>>>(bsum, boff, nb);
    k_place<<<eb, 256, 0, stream>>>(src, dst, ew, seq, incl, cnt, boff, sliceoff, csr, N_EDGES);
    k_deg<<<nb, 256, 0, stream>>>(csr, incl, cnt, boff, dis, selfnorm, N_NODES);
    k_normw<<<nb, 256, 0, stream>>>(csr, incl, cnt, boff, dis, N_NODES);

    const int gX = (N_NODES + 127) / 128;   // 782
    const int HALF = N_NODES / 2;           // 50000

    // ---- layer 1: g1 = A*X (128-wide gather), H1 = relu(g1 @ W0 + b0) ----
    agg_csr<F_IN, 16, false, false><<<(N_NODES + 15) / 16, 256, 0, stream>>>(
        xh, csr, incl, cnt, boff, selfnorm, nullptr, bufA, 0, N_NODES);
    gemm_mfma<F_IN, HID, true><<<gX * (HID / 64), 256, 0, stream>>>(bufA, Wt0, b0, bufB, N_NODES);

    // ---- layer 2: g2 = A*H1 (split for visibility), H2 = relu(g2 @ W1 + b1) ----
    agg_csr<HID, 32, false, false><<<HALF / 8, 256, 0, stream>>>(
        bufB, csr, incl, cnt, boff, selfnorm, nullptr, bufA, 0, HALF);
    agg_csr<HID, 32, false, false><<<(N_NODES - HALF + 7) / 8, 256, 0, stream>>>(
        bufB, csr, incl, cnt, boff, selfnorm, nullptr, bufA, HALF, N_NODES);
    gemm_mfma<HID, HID, true><<<gX * (HID / 64), 256, 0, stream>>>(bufA, Wt1, b1, bufB, N_NODES);

    // ---- layer 3: P = H2 @ W2 (no act), out = A*P + b2 ----
    gemm_mfma<HID, NCLS, false><<<gX * (NCLS / 64), 256, 0, stream>>>(bufB, Wt2, nullptr, bufA, N_NODES);
    agg_csr<NCLS, 8, true, true><<<(N_NODES + 31) / 32, 256, 0, stream>>>(
        bufA, csr, incl, cnt, boff, selfnorm, b2, outp, 0, N_NODES);
}

// Round 11
// 547.495 us; speedup vs baseline: 1.0453x; 1.0453x over previous
//
#include <hip/hip_runtime.h>

#define N_NODES 100000
#define F_IN 128
#define HID 256
#define NCLS 64
#define N_EDGES 1600000

typedef _Float16 f16;
typedef f16 half8 __attribute__((ext_vector_type(8)));
typedef f16 half4 __attribute__((ext_vector_type(4)));
typedef float f32x4 __attribute__((ext_vector_type(4)));
typedef unsigned long long u64;
typedef unsigned short u16;
typedef unsigned int u32;

#define FIXED_SCALE 67108864.0f   // 2^26

// ---------------------------------------------------------------------------
// R11 CSR build: u64 atomics (count<<40 | fixed26 weight) sharded 8-way
// (degp8[j][node], j=bid&7). R10 taught: sharding+narrowing bought 94->79 but
// deferred normalization (k_deg+k_normw) cost +30 -> net loss; and R6's
// scan3-fold moved a 2us pass into per-edge random reads (-> R4 row[] is
// restored). Here the weight rides the atomic again (u64), so dis/selfnorm
// come out of k_scan1 and k_place normalizes inline -- no extra csr passes.
// Shard correctness is value-agnostic: seq=(j<<12|slot); pos = row[d] +
// sliceoff[d][j] + slot is unique for any stable per-block j. Weight-sum
// safety: total fixed26 degree < 2^31 << 2^40, so the 8 shard u64s add
// without the count field being corrupted.
// ---------------------------------------------------------------------------
__global__ void k_init(u64* __restrict__ degp8, int n8) {
    int i = blockIdx.x * 256 + threadIdx.x;
    if (i < n8) degp8[i] = (i < N_NODES) ? (u64)(1u << 26) : 0ull;  // self-loop in shard 0
}

#define EB4  1563    // ceil(N_EDGES/1024)
#define XB   12500   // N_NODES*F_IN/4/256
#define W0B  128     // F_IN*HID/256
#define W1B  256     // HID*HID/256
#define W2B  64      // HID*NCLS/256
__global__ __launch_bounds__(256) void mega1(
        const int* __restrict__ dst, const float* __restrict__ ew,
        u64* __restrict__ degp8, u16* __restrict__ seq,
        const float* __restrict__ x, f16* __restrict__ xh,
        const float* __restrict__ W0, f16* __restrict__ Wt0,
        const float* __restrict__ W1, f16* __restrict__ Wt1,
        const float* __restrict__ W2, f16* __restrict__ Wt2) {
    int bid = blockIdx.x;
    int t = threadIdx.x;
    if (bid < EB4) {
        const int j = bid & 7;                       // shard
        u64* myp = degp8 + (size_t)j * N_NODES;
        int base = bid * 1024 + t;
        int d[4]; u64 c[4], old[4]; bool ok[4];
        #pragma unroll
        for (int u = 0; u < 4; ++u) {
            int i = base + u * 256;
            ok[u] = (i < N_EDGES);
            if (ok[u]) {
                d[u] = dst[i];
                c[u] = (1ULL << 40) |
                    (u64)__float2uint_rn(ew[i] * FIXED_SCALE);
            }
        }
        #pragma unroll
        for (int u = 0; u < 4; ++u)
            if (ok[u]) old[u] = atomicAdd(&myp[d[u]], c[u]);
        #pragma unroll
        for (int u = 0; u < 4; ++u)
            if (ok[u]) seq[base + u * 256] = (u16)((j << 12) | (u32)(old[u] >> 40));
    } else if (bid < EB4 + XB) {
        int i = (bid - EB4) * 256 + t;       // float4 index over x
        if (i < N_NODES * (F_IN / 4)) {
            float4 v = *(const float4*)&x[(size_t)i * 4];
            half4 o;
            o[0] = (f16)v.x; o[1] = (f16)v.y; o[2] = (f16)v.z; o[3] = (f16)v.w;
            *(half4*)&xh[(size_t)i * 4] = o;
        }
    } else if (bid < EB4 + XB + W0B) {
        int i = (bid - EB4 - XB) * 256 + t;  // W0[F_IN][HID] -> Wt0[HID][F_IN]
        int k = i / HID, dd = i % HID;
        Wt0[dd * F_IN + k] = (f16)W0[i];
    } else if (bid < EB4 + XB + W0B + W1B) {
        int i = (bid - EB4 - XB - W0B) * 256 + t;
        int k = i / HID, dd = i % HID;
        Wt1[dd * HID + k] = (f16)W1[i];
    } else {
        int i = (bid - EB4 - XB - W0B - W1B) * 256 + t;
        int k = i / NCLS, dd = i % NCLS;     // W2[HID][NCLS] -> Wt2[NCLS][HID]
        Wt2[dd * HID + k] = (f16)W2[i];
    }
}

// Sum 8 shards -> cnt, weighted degree -> dis/selfnorm, per-shard exclusive
// offsets (sliceoff u16[8], node-major), within-block inclusive scan -> incl.
__global__ void k_scan1(const u64* __restrict__ degp8,
                        int* __restrict__ cnt, float* __restrict__ dis,
                        float* __restrict__ selfnorm, u16* __restrict__ sliceoff,
                        int* __restrict__ incl, int* __restrict__ bsum, int n) {
    __shared__ int s[256];
    int t = threadIdx.x;
    int i = blockIdx.x * 256 + t;
    int v = 0;
    if (i < n) {
        u32 off = 0;
        u64 wsum = 0;
        u16 so[8];
        #pragma unroll
        for (int j = 0; j < 8; ++j) {
            u64 p = degp8[(size_t)j * N_NODES + i];
            so[j] = (u16)off;
            off += (u32)(p >> 40);
            wsum += (p & ((1ULL << 40) - 1));
        }
        v = (int)off;
        cnt[i] = v;
        float deg = (float)wsum * (1.0f / FIXED_SCALE);
        float d = rsqrtf(deg);
        dis[i] = d;
        selfnorm[i] = d * d;
        uint4 p4;
        p4.x = (u32)so[0] | ((u32)so[1] << 16);
        p4.y = (u32)so[2] | ((u32)so[3] << 16);
        p4.z = (u32)so[4] | ((u32)so[5] << 16);
        p4.w = (u32)so[6] | ((u32)so[7] << 16);
        *(uint4*)&sliceoff[(size_t)i * 8] = p4;
    }
    s[t] = v;
    __syncthreads();
    #pragma unroll
    for (int off = 1; off < 256; off <<= 1) {
        int x = (t >= off) ? s[t - off] : 0;
        __syncthreads();
        s[t] += x;
        __syncthreads();
    }
    if (i < n) incl[i] = s[t];
    if (t == 255) bsum[blockIdx.x] = s[255];
}

__global__ void k_scan2(const int* __restrict__ bsum, int* __restrict__ boff, int nb) {
    __shared__ int s[512];
    int t = threadIdx.x;
    int v = (t < nb) ? bsum[t] : 0;
    s[t] = v;
    __syncthreads();
    #pragma unroll
    for (int off = 1; off < 512; off <<= 1) {
        int x = (t >= off) ? s[t - off] : 0;
        __syncthreads();
        s[t] += x;
        __syncthreads();
    }
    if (t < nb) boff[t] = s[t] - v;
}

// row[i] = global segment start (R4-style dedicated array; R6's fold of this
// into per-edge reads cost ~15us -- do not re-fold).
__global__ void k_scan3(int* __restrict__ row, const int* __restrict__ incl,
                        const int* __restrict__ cnt, const int* __restrict__ boff, int n) {
    int i = blockIdx.x * 256 + threadIdx.x;
    if (i < n) row[i] = incl[i] - cnt[i] + boff[i >> 8];
}

// atomic-free placement of NORMALIZED weights:
// pos = row[d] + sliceoff[d][j] + slot
__global__ void k_place(const int* __restrict__ src, const int* __restrict__ dst,
                        const float* __restrict__ w, const u16* __restrict__ seq,
                        const int* __restrict__ row, const u16* __restrict__ sliceoff,
                        const float* __restrict__ dis,
                        int2* __restrict__ csr, int e) {
    int i = blockIdx.x * 256 + threadIdx.x;
    if (i < e) {
        int s = src[i], d = dst[i];
        float nw = dis[s] * w[i] * dis[d];
        u16 sq = seq[i];
        int pos = row[d] + (int)sliceoff[(size_t)d * 8 + (sq >> 12)] + (int)(sq & 0xFFF);
        csr[pos] = make_int2(s, __float_as_int(nw));
    }
}

// ---------------------------------------------------------------------------
// MFMA GEMM: out[n, c] = sum_k in[n, k] * W[k, c]  (+bias, relu if BIAS_RELU)
// Block tile 128x64, 4 waves. VGPR-staging body (verified); 1D grid +
// bijective XCD-chunk swizzle. global_load_lds variant suspect in container
// failures -- not reintroduced. agg-GEMM fusion structurally dead (R5/R6).
// ---------------------------------------------------------------------------
template <int K, int DOUT, bool BIAS_RELU>
__global__ __launch_bounds__(256) void gemm_mfma(const f16* __restrict__ in,
                                                 const f16* __restrict__ Wt,  // [DOUT][K]
                                                 const float* __restrict__ bias,
                                                 f16* __restrict__ out,
                                                 int nNodes) {
    constexpr int BM = 128, BN = 64, BK = 32;
    constexpr int NB = DOUT / BN;
    constexpr int AP = 40;
    constexpr int CP = 72;
    constexpr int SMEM = (BM * AP + BN * AP) > (BM * CP) ? (BM * AP + BN * AP) : (BM * CP);
    __shared__ f16 smem[SMEM];
    f16* As = smem;
    f16* Bs = smem + BM * AP;

    const int nwg = gridDim.x;
    const int b = blockIdx.x;
    const int q = nwg >> 3, r = nwg & 7, xcd = b & 7;
    const int wk = (xcd < r ? xcd * (q + 1) : r * (q + 1) + (xcd - r) * q) + (b >> 3);
    const int bx = wk / NB, by = wk % NB;

    const int t = threadIdx.x;
    const int w = t >> 6;
    const int lane = t & 63;
    const int quad = lane >> 4;
    const int l16 = lane & 15;
    const int nodeBase = bx * BM;
    const int colBase = by * BN;

    f32x4 acc[2][4] = {};

    for (int k0 = 0; k0 < K; k0 += BK) {
        {
            int koff = (t & 3) * 8;
            #pragma unroll
            for (int p = 0; p < 2; ++p) {
                int r2 = (t >> 2) + p * 64;
                int gn = nodeBase + r2;
                if (gn >= nNodes) gn = nNodes - 1;
                half8 v = *(const half8*)&in[(size_t)gn * K + k0 + koff];
                *(half8*)&As[r2 * AP + koff] = v;
            }
        }
        {
            int koff = (t & 3) * 8;
            int c = t >> 2;
            half8 v = *(const half8*)&Wt[(size_t)(colBase + c) * K + k0 + koff];
            *(half8*)&Bs[c * AP + koff] = v;
        }
        __syncthreads();

        half8 a[2];
        #pragma unroll
        for (int rt = 0; rt < 2; ++rt)
            a[rt] = *(const half8*)&As[(w * 32 + rt * 16 + l16) * AP + quad * 8];
        #pragma unroll
        for (int ct = 0; ct < 4; ++ct) {
            half8 bf = *(const half8*)&Bs[(ct * 16 + l16) * AP + quad * 8];
            acc[0][ct] = __builtin_amdgcn_mfma_f32_16x16x32_f16(a[0], bf, acc[0][ct], 0, 0, 0);
            acc[1][ct] = __builtin_amdgcn_mfma_f32_16x16x32_f16(a[1], bf, acc[1][ct], 0, 0, 0);
        }
        __syncthreads();
    }

    float bv[4];
    #pragma unroll
    for (int ct = 0; ct < 4; ++ct)
        bv[ct] = BIAS_RELU ? bias[colBase + ct * 16 + l16] : 0.0f;

    f16* Cs = smem;
    #pragma unroll
    for (int rt = 0; rt < 2; ++rt)
        #pragma unroll
        for (int ct = 0; ct < 4; ++ct)
            #pragma unroll
            for (int rr2 = 0; rr2 < 4; ++rr2) {
                int rr = w * 32 + rt * 16 + quad * 4 + rr2;
                int cc = ct * 16 + l16;
                float v = acc[rt][ct][rr2];
                if (BIAS_RELU) v = fmaxf(v + bv[ct], 0.0f);
                Cs[rr * CP + cc] = (f16)v;
            }
    __syncthreads();
    #pragma unroll
    for (int p = 0; p < 4; ++p) {
        int rr = (t >> 3) + p * 32;
        int gn = nodeBase + rr;
        int chunk = (t & 7) * 8;
        if (gn < nNodes)
            *(half8*)&out[(size_t)gn * DOUT + colBase + chunk] =
                *(const half8*)&Cs[rr * CP + chunk];
    }
}

// ---------------------------------------------------------------------------
// CSR aggregation: out[d,:] = sn[d]*h[d,:] (+bias) + sum_e w_e*h[src_e,:]
// Unroll-2 (R4: unroll-4 null; gather BW-bound at ~3.8 TB/s pattern ceiling,
// FETCH at the 8-XCD compulsory floor). row[] restored (R4-style).
// ---------------------------------------------------------------------------
template <int DOUT, int TPN, bool HAS_BIAS, bool OUT_F32>
__global__ __launch_bounds__(256) void agg_csr(const f16* __restrict__ h,
                                               const int2* __restrict__ csr,
                                               const int* __restrict__ row,
                                               const int* __restrict__ cnt,
                                               const float* __restrict__ sn,
                                               const float* __restrict__ bias,
                                               void* __restrict__ outv,
                                               int nodeBase, int nodeEnd) {
    constexpr int NPB = 256 / TPN;
    int node = nodeBase + blockIdx.x * NPB + threadIdx.x / TPN;
    if (node >= nodeEnd) return;
    int lane = threadIdx.x % TPN;
    int col = lane * 8;

    float s = sn[node];
    half8 hv = *(const half8*)&h[(size_t)node * DOUT + col];
    float acc[8];
    #pragma unroll
    for (int i = 0; i < 8; ++i)
        acc[i] = s * (float)hv[i] + (HAS_BIAS ? bias[col + i] : 0.0f);

    int e = row[node];
    int end = e + cnt[node];

    for (; e + 1 < end; e += 2) {
        int2 e0 = csr[e], e1 = csr[e + 1];
        float w0 = __int_as_float(e0.y), w1 = __int_as_float(e1.y);
        half8 a0 = *(const half8*)&h[(size_t)e0.x * DOUT + col];
        half8 a1 = *(const half8*)&h[(size_t)e1.x * DOUT + col];
        #pragma unroll
        for (int i = 0; i < 8; ++i) acc[i] += w0 * (float)a0[i] + w1 * (float)a1[i];
    }
    if (e < end) {
        int2 e0 = csr[e];
        float w0 = __int_as_float(e0.y);
        half8 a0 = *(const half8*)&h[(size_t)e0.x * DOUT + col];
        #pragma unroll
        for (int i = 0; i < 8; ++i) acc[i] += w0 * (float)a0[i];
    }

    if (OUT_F32) {
        float* out = (float*)outv;
        float4 r0 = make_float4(acc[0], acc[1], acc[2], acc[3]);
        float4 r1 = make_float4(acc[4], acc[5], acc[6], acc[7]);
        *(float4*)&out[(size_t)node * DOUT + col] = r0;
        *(float4*)&out[(size_t)node * DOUT + col + 4] = r1;
    } else {
        f16* out = (f16*)outv;
        half8 o;
        #pragma unroll
        for (int i = 0; i < 8; ++i) o[i] = (f16)acc[i];
        *(half8*)&out[(size_t)node * DOUT + col] = o;
    }
}

// ---------------------------------------------------------------------------
extern "C" void kernel_launch(void* const* d_in, const int* in_sizes, int n_in,
                              void* d_out, int out_size, void* d_ws, size_t ws_size,
                              hipStream_t stream) {
    const float* x  = (const float*)d_in[0];
    const int*   ei = (const int*)d_in[1];
    const float* ew = (const float*)d_in[2];
    const float* W0 = (const float*)d_in[3];
    const float* b0 = (const float*)d_in[4];
    const float* W1 = (const float*)d_in[5];
    const float* b1 = (const float*)d_in[6];
    const float* W2 = (const float*)d_in[7];
    const float* b2 = (const float*)d_in[8];
    const int* src = ei;
    const int* dst = ei + N_EDGES;
    float* outp = (float*)d_out;

    // workspace carve-up (8B-aligned first)
    char* ws = (char*)d_ws;
    u64*   degp8    = (u64*)ws;    ws += (size_t)8 * N_NODES * 8;   // 6.4MB
    int2*  csr      = (int2*)ws;   ws += (size_t)N_EDGES * 8;
    u16*   seq      = (u16*)ws;    ws += (size_t)N_EDGES * 4;       // u16 used
    u16*   sliceoff = (u16*)ws;    ws += (size_t)N_NODES * 8 * 2;   // 1.6MB
    float* dis      = (float*)ws;  ws += N_NODES * 4;
    float* selfnorm = (float*)ws;  ws += N_NODES * 4;
    int*   cnt      = (int*)ws;    ws += N_NODES * 4;
    int*   incl     = (int*)ws;    ws += N_NODES * 4;
    int*   row      = (int*)ws;    ws += N_NODES * 4;
    int*   bsum     = (int*)ws;    ws += 512 * 4;
    int*   boff     = (int*)ws;    ws += 512 * 4;
    f16*   xh       = (f16*)ws;    ws += (size_t)N_NODES * F_IN * 2;
    f16*   Wt0      = (f16*)ws;    ws += F_IN * HID * 2;
    f16*   Wt1      = (f16*)ws;    ws += HID * HID * 2;
    f16*   Wt2      = (f16*)ws;    ws += HID * NCLS * 2;
    f16*   bufA     = (f16*)ws;    ws += (size_t)N_NODES * HID * 2;
    f16*   bufB     = (f16*)ws;    ws += (size_t)N_NODES * HID * 2;

    const int nb = (N_NODES + 255) / 256;   // 391
    const int eb = (N_EDGES + 255) / 256;   // 6250

    // ---- CSR build + norm (conversions hidden under the atomic pass) ----
    k_init<<<(8 * N_NODES + 255) / 256, 256, 0, stream>>>(degp8, 8 * N_NODES);
    mega1<<<EB4 + XB + W0B + W1B + W2B, 256, 0, stream>>>(
        dst, ew, degp8, seq, x, xh, W0, Wt0, W1, Wt1, W2, Wt2);
    k_scan1<<<nb, 256, 0, stream>>>(degp8, cnt, dis, selfnorm, sliceoff, incl, bsum, N_NODES);
    k_scan2<<<1, 512, 0, stream>>>(bsum, boff, nb);
    k_scan3<<<nb, 256, 0, stream>>>(row, incl, cnt, boff, N_NODES);
    k_place<<<eb, 256, 0, stream>>>(src, dst, ew, seq, row, sliceoff, dis, csr, N_EDGES);

    const int gX = (N_NODES + 127) / 128;   // 782
    const int HALF = N_NODES / 2;           // 50000

    // ---- layer 1: g1 = A*X (128-wide gather), H1 = relu(g1 @ W0 + b0) ----
    agg_csr<F_IN, 16, false, false><<<(N_NODES + 15) / 16, 256, 0, stream>>>(
        xh, csr, row, cnt, selfnorm, nullptr, bufA, 0, N_NODES);
    gemm_mfma<F_IN, HID, true><<<gX * (HID / 64), 256, 0, stream>>>(bufA, Wt0, b0, bufB, N_NODES);

    // ---- layer 2: g2 = A*H1 (split keeps mega1 visible in top-5),
    //      H2 = relu(g2 @ W1 + b1) ----
    agg_csr<HID, 32, false, false><<<HALF / 8, 256, 0, stream>>>(
        bufB, csr, row, cnt, selfnorm, nullptr, bufA, 0, HALF);
    agg_csr<HID, 32, false, false><<<(N_NODES - HALF + 7) / 8, 256, 0, stream>>>(
        bufB, csr, row, cnt, selfnorm, nullptr, bufA, HALF, N_NODES);
    gemm_mfma<HID, HID, true><<<gX * (HID / 64), 256, 0, stream>>>(bufA, Wt1, b1, bufB, N_NODES);

    // ---- layer 3: P = H2 @ W2 (no act), out = A*P + b2 ----
    gemm_mfma<HID, NCLS, false><<<gX * (NCLS / 64), 256, 0, stream>>>(bufB, Wt2, nullptr, bufA, N_NODES);
    agg_csr<NCLS, 8, true, true><<<(N_NODES + 31) / 32, 256, 0, stream>>>(
        bufA, csr, row, cnt, selfnorm, b2, outp, 0, N_NODES);
}

// Round 12
// 539.130 us; speedup vs baseline: 1.0616x; 1.0155x over previous
//
#include <hip/hip_runtime.h>

#define N_NODES 100000
#define F_IN 128
#define HID 256
#define NCLS 64
#define N_EDGES 1600000

typedef _Float16 f16;
typedef f16 half8 __attribute__((ext_vector_type(8)));
typedef f16 half4 __attribute__((ext_vector_type(4)));
typedef float f32x4 __attribute__((ext_vector_type(4)));
typedef unsigned long long u64;
typedef unsigned short u16;
typedef unsigned int u32;

#define FIXED_SCALE 67108864.0f   // 2^26

// ---------------------------------------------------------------------------
// CSR build: u64 atomics (count<<40 | fixed26 weight) sharded 8-way
// (degp8[j][node], j=bid&7). Atomic-rate matrix (R7-R11): unsharded u64 92.5,
// 4-deep 94, sharded u32 79.4, sharded u64 89 -> device scattered-RMW ceiling
// ~18-20 ops/ns; only width moves it, and the u32 path's deferred-norm tax
// (+30us, R10) exceeds its -10us. Weight rides the atomic so dis/selfnorm
// come from k_scan1 and k_place normalizes inline (no extra csr passes).
// Shard correctness is value-agnostic: seq=(j<<12|slot); pos = row[d] +
// sliceoff[d][j] + slot is unique for any stable per-block j. Weight-sum
// safety: total fixed26 degree < 2^31 << 2^40.
// ---------------------------------------------------------------------------
__global__ void k_init(u64* __restrict__ degp8, int n8) {
    int i = blockIdx.x * 256 + threadIdx.x;
    if (i < n8) degp8[i] = (i < N_NODES) ? (u64)(1u << 26) : 0ull;  // self-loop in shard 0
}

#define EB4  1563    // ceil(N_EDGES/1024)
#define XB   12500   // N_NODES*F_IN/4/256
#define W0B  128     // F_IN*HID/256
#define W1B  256     // HID*HID/256
#define W2B  64      // HID*NCLS/256
__global__ __launch_bounds__(256) void mega1(
        const int* __restrict__ dst, const float* __restrict__ ew,
        u64* __restrict__ degp8, u16* __restrict__ seq,
        const float* __restrict__ x, f16* __restrict__ xh,
        const float* __restrict__ W0, f16* __restrict__ Wt0,
        const float* __restrict__ W1, f16* __restrict__ Wt1,
        const float* __restrict__ W2, f16* __restrict__ Wt2) {
    int bid = blockIdx.x;
    int t = threadIdx.x;
    if (bid < EB4) {
        const int j = bid & 7;                       // shard
        u64* myp = degp8 + (size_t)j * N_NODES;
        int base = bid * 1024 + t;
        int d[4]; u64 c[4], old[4]; bool ok[4];
        #pragma unroll
        for (int u = 0; u < 4; ++u) {
            int i = base + u * 256;
            ok[u] = (i < N_EDGES);
            if (ok[u]) {
                d[u] = dst[i];
                c[u] = (1ULL << 40) |
                    (u64)__float2uint_rn(ew[i] * FIXED_SCALE);
            }
        }
        #pragma unroll
        for (int u = 0; u < 4; ++u)
            if (ok[u]) old[u] = atomicAdd(&myp[d[u]], c[u]);
        #pragma unroll
        for (int u = 0; u < 4; ++u)
            if (ok[u]) seq[base + u * 256] = (u16)((j << 12) | (u32)(old[u] >> 40));
    } else if (bid < EB4 + XB) {
        int i = (bid - EB4) * 256 + t;       // float4 index over x
        if (i < N_NODES * (F_IN / 4)) {
            float4 v = *(const float4*)&x[(size_t)i * 4];
            half4 o;
            o[0] = (f16)v.x; o[1] = (f16)v.y; o[2] = (f16)v.z; o[3] = (f16)v.w;
            *(half4*)&xh[(size_t)i * 4] = o;
        }
    } else if (bid < EB4 + XB + W0B) {
        int i = (bid - EB4 - XB) * 256 + t;  // W0[F_IN][HID] -> Wt0[HID][F_IN]
        int k = i / HID, dd = i % HID;
        Wt0[dd * F_IN + k] = (f16)W0[i];
    } else if (bid < EB4 + XB + W0B + W1B) {
        int i = (bid - EB4 - XB - W0B) * 256 + t;
        int k = i / HID, dd = i % HID;
        Wt1[dd * HID + k] = (f16)W1[i];
    } else {
        int i = (bid - EB4 - XB - W0B - W1B) * 256 + t;
        int k = i / NCLS, dd = i % NCLS;     // W2[HID][NCLS] -> Wt2[NCLS][HID]
        Wt2[dd * HID + k] = (f16)W2[i];
    }
}

// Sum 8 shards -> cnt, weighted degree -> dis/selfnorm, per-shard exclusive
// offsets (sliceoff u16[8], node-major), within-block inclusive scan -> incl.
__global__ void k_scan1(const u64* __restrict__ degp8,
                        int* __restrict__ cnt, float* __restrict__ dis,
                        float* __restrict__ selfnorm, u16* __restrict__ sliceoff,
                        int* __restrict__ incl, int* __restrict__ bsum, int n) {
    __shared__ int s[256];
    int t = threadIdx.x;
    int i = blockIdx.x * 256 + t;
    int v = 0;
    if (i < n) {
        u32 off = 0;
        u64 wsum = 0;
        u16 so[8];
        #pragma unroll
        for (int j = 0; j < 8; ++j) {
            u64 p = degp8[(size_t)j * N_NODES + i];
            so[j] = (u16)off;
            off += (u32)(p >> 40);
            wsum += (p & ((1ULL << 40) - 1));
        }
        v = (int)off;
        cnt[i] = v;
        float deg = (float)wsum * (1.0f / FIXED_SCALE);
        float d = rsqrtf(deg);
        dis[i] = d;
        selfnorm[i] = d * d;
        uint4 p4;
        p4.x = (u32)so[0] | ((u32)so[1] << 16);
        p4.y = (u32)so[2] | ((u32)so[3] << 16);
        p4.z = (u32)so[4] | ((u32)so[5] << 16);
        p4.w = (u32)so[6] | ((u32)so[7] << 16);
        *(uint4*)&sliceoff[(size_t)i * 8] = p4;
    }
    s[t] = v;
    __syncthreads();
    #pragma unroll
    for (int off = 1; off < 256; off <<= 1) {
        int x = (t >= off) ? s[t - off] : 0;
        __syncthreads();
        s[t] += x;
        __syncthreads();
    }
    if (i < n) incl[i] = s[t];
    if (t == 255) bsum[blockIdx.x] = s[255];
}

__global__ void k_scan2(const int* __restrict__ bsum, int* __restrict__ boff, int nb) {
    __shared__ int s[512];
    int t = threadIdx.x;
    int v = (t < nb) ? bsum[t] : 0;
    s[t] = v;
    __syncthreads();
    #pragma unroll
    for (int off = 1; off < 512; off <<= 1) {
        int x = (t >= off) ? s[t - off] : 0;
        __syncthreads();
        s[t] += x;
        __syncthreads();
    }
    if (t < nb) boff[t] = s[t] - v;
}

// row[i] = global segment start (dedicated array; R6's fold of this into
// per-edge reads cost ~15us -- do not re-fold).
__global__ void k_scan3(int* __restrict__ row, const int* __restrict__ incl,
                        const int* __restrict__ cnt, const int* __restrict__ boff, int n) {
    int i = blockIdx.x * 256 + threadIdx.x;
    if (i < n) row[i] = incl[i] - cnt[i] + boff[i >> 8];
}

// atomic-free placement of NORMALIZED weights:
// pos = row[d] + sliceoff[d][j] + slot
__global__ void k_place(const int* __restrict__ src, const int* __restrict__ dst,
                        const float* __restrict__ w, const u16* __restrict__ seq,
                        const int* __restrict__ row, const u16* __restrict__ sliceoff,
                        const float* __restrict__ dis,
                        int2* __restrict__ csr, int e) {
    int i = blockIdx.x * 256 + threadIdx.x;
    if (i < e) {
        int s = src[i], d = dst[i];
        float nw = dis[s] * w[i] * dis[d];
        u16 sq = seq[i];
        int pos = row[d] + (int)sliceoff[(size_t)d * 8 + (sq >> 12)] + (int)(sq & 0xFFF);
        csr[pos] = make_int2(s, __float_as_int(nw));
    }
}

// ---------------------------------------------------------------------------
// MFMA GEMM: out[n, c] = sum_k in[n, k] * W[k, c]  (+bias, relu if BIAS_RELU)
// Block tile 128x64, 4 waves. VGPR-staging body (verified); 1D grid +
// bijective XCD-chunk swizzle. global_load_lds variant suspect in container
// failures -- not reintroduced. agg-GEMM fusion structurally dead (R5/R6).
// ---------------------------------------------------------------------------
template <int K, int DOUT, bool BIAS_RELU>
__global__ __launch_bounds__(256) void gemm_mfma(const f16* __restrict__ in,
                                                 const f16* __restrict__ Wt,  // [DOUT][K]
                                                 const float* __restrict__ bias,
                                                 f16* __restrict__ out,
                                                 int nNodes) {
    constexpr int BM = 128, BN = 64, BK = 32;
    constexpr int NB = DOUT / BN;
    constexpr int AP = 40;
    constexpr int CP = 72;
    constexpr int SMEM = (BM * AP + BN * AP) > (BM * CP) ? (BM * AP + BN * AP) : (BM * CP);
    __shared__ f16 smem[SMEM];
    f16* As = smem;
    f16* Bs = smem + BM * AP;

    const int nwg = gridDim.x;
    const int b = blockIdx.x;
    const int q = nwg >> 3, r = nwg & 7, xcd = b & 7;
    const int wk = (xcd < r ? xcd * (q + 1) : r * (q + 1) + (xcd - r) * q) + (b >> 3);
    const int bx = wk / NB, by = wk % NB;

    const int t = threadIdx.x;
    const int w = t >> 6;
    const int lane = t & 63;
    const int quad = lane >> 4;
    const int l16 = lane & 15;
    const int nodeBase = bx * BM;
    const int colBase = by * BN;

    f32x4 acc[2][4] = {};

    for (int k0 = 0; k0 < K; k0 += BK) {
        {
            int koff = (t & 3) * 8;
            #pragma unroll
            for (int p = 0; p < 2; ++p) {
                int r2 = (t >> 2) + p * 64;
                int gn = nodeBase + r2;
                if (gn >= nNodes) gn = nNodes - 1;
                half8 v = *(const half8*)&in[(size_t)gn * K + k0 + koff];
                *(half8*)&As[r2 * AP + koff] = v;
            }
        }
        {
            int koff = (t & 3) * 8;
            int c = t >> 2;
            half8 v = *(const half8*)&Wt[(size_t)(colBase + c) * K + k0 + koff];
            *(half8*)&Bs[c * AP + koff] = v;
        }
        __syncthreads();

        half8 a[2];
        #pragma unroll
        for (int rt = 0; rt < 2; ++rt)
            a[rt] = *(const half8*)&As[(w * 32 + rt * 16 + l16) * AP + quad * 8];
        #pragma unroll
        for (int ct = 0; ct < 4; ++ct) {
            half8 bf = *(const half8*)&Bs[(ct * 16 + l16) * AP + quad * 8];
            acc[0][ct] = __builtin_amdgcn_mfma_f32_16x16x32_f16(a[0], bf, acc[0][ct], 0, 0, 0);
            acc[1][ct] = __builtin_amdgcn_mfma_f32_16x16x32_f16(a[1], bf, acc[1][ct], 0, 0, 0);
        }
        __syncthreads();
    }

    float bv[4];
    #pragma unroll
    for (int ct = 0; ct < 4; ++ct)
        bv[ct] = BIAS_RELU ? bias[colBase + ct * 16 + l16] : 0.0f;

    f16* Cs = smem;
    #pragma unroll
    for (int rt = 0; rt < 2; ++rt)
        #pragma unroll
        for (int ct = 0; ct < 4; ++ct)
            #pragma unroll
            for (int rr2 = 0; rr2 < 4; ++rr2) {
                int rr = w * 32 + rt * 16 + quad * 4 + rr2;
                int cc = ct * 16 + l16;
                float v = acc[rt][ct][rr2];
                if (BIAS_RELU) v = fmaxf(v + bv[ct], 0.0f);
                Cs[rr * CP + cc] = (f16)v;
            }
    __syncthreads();
    #pragma unroll
    for (int p = 0; p < 4; ++p) {
        int rr = (t >> 3) + p * 32;
        int gn = nodeBase + rr;
        int chunk = (t & 7) * 8;
        if (gn < nNodes)
            *(half8*)&out[(size_t)gn * DOUT + colBase + chunk] =
                *(const half8*)&Cs[rr * CP + chunk];
    }
}

// ---------------------------------------------------------------------------
// CSR aggregation: out[d,:] = sn[d]*h[d,:] (+bias) + sum_e w_e*h[src_e,:]
// Unroll-2 (R4: unroll-4 null; gather BW-bound at ~3.8 TB/s scattered-64B
// pattern ceiling, FETCH at the 8-XCD compulsory floor; column-slicing
// refuted by L2-hit arithmetic in R12 analysis).
// ---------------------------------------------------------------------------
template <int DOUT, int TPN, bool HAS_BIAS, bool OUT_F32>
__global__ __launch_bounds__(256) void agg_csr(const f16* __restrict__ h,
                                               const int2* __restrict__ csr,
                                               const int* __restrict__ row,
                                               const int* __restrict__ cnt,
                                               const float* __restrict__ sn,
                                               const float* __restrict__ bias,
                                               void* __restrict__ outv,
                                               int nNodes) {
    constexpr int NPB = 256 / TPN;
    int node = blockIdx.x * NPB + threadIdx.x / TPN;
    if (node >= nNodes) return;
    int lane = threadIdx.x % TPN;
    int col = lane * 8;

    float s = sn[node];
    half8 hv = *(const half8*)&h[(size_t)node * DOUT + col];
    float acc[8];
    #pragma unroll
    for (int i = 0; i < 8; ++i)
        acc[i] = s * (float)hv[i] + (HAS_BIAS ? bias[col + i] : 0.0f);

    int e = row[node];
    int end = e + cnt[node];

    for (; e + 1 < end; e += 2) {
        int2 e0 = csr[e], e1 = csr[e + 1];
        float w0 = __int_as_float(e0.y), w1 = __int_as_float(e1.y);
        half8 a0 = *(const half8*)&h[(size_t)e0.x * DOUT + col];
        half8 a1 = *(const half8*)&h[(size_t)e1.x * DOUT + col];
        #pragma unroll
        for (int i = 0; i < 8; ++i) acc[i] += w0 * (float)a0[i] + w1 * (float)a1[i];
    }
    if (e < end) {
        int2 e0 = csr[e];
        float w0 = __int_as_float(e0.y);
        half8 a0 = *(const half8*)&h[(size_t)e0.x * DOUT + col];
        #pragma unroll
        for (int i = 0; i < 8; ++i) acc[i] += w0 * (float)a0[i];
    }

    if (OUT_F32) {
        float* out = (float*)outv;
        float4 r0 = make_float4(acc[0], acc[1], acc[2], acc[3]);
        float4 r1 = make_float4(acc[4], acc[5], acc[6], acc[7]);
        *(float4*)&out[(size_t)node * DOUT + col] = r0;
        *(float4*)&out[(size_t)node * DOUT + col + 4] = r1;
    } else {
        f16* out = (f16*)outv;
        half8 o;
        #pragma unroll
        for (int i = 0; i < 8; ++i) o[i] = (f16)acc[i];
        *(half8*)&out[(size_t)node * DOUT + col] = o;
    }
}

// ---------------------------------------------------------------------------
extern "C" void kernel_launch(void* const* d_in, const int* in_sizes, int n_in,
                              void* d_out, int out_size, void* d_ws, size_t ws_size,
                              hipStream_t stream) {
    const float* x  = (const float*)d_in[0];
    const int*   ei = (const int*)d_in[1];
    const float* ew = (const float*)d_in[2];
    const float* W0 = (const float*)d_in[3];
    const float* b0 = (const float*)d_in[4];
    const float* W1 = (const float*)d_in[5];
    const float* b1 = (const float*)d_in[6];
    const float* W2 = (const float*)d_in[7];
    const float* b2 = (const float*)d_in[8];
    const int* src = ei;
    const int* dst = ei + N_EDGES;
    float* outp = (float*)d_out;

    // workspace carve-up (8B-aligned first)
    char* ws = (char*)d_ws;
    u64*   degp8    = (u64*)ws;    ws += (size_t)8 * N_NODES * 8;   // 6.4MB
    int2*  csr      = (int2*)ws;   ws += (size_t)N_EDGES * 8;
    u16*   seq      = (u16*)ws;    ws += (size_t)N_EDGES * 4;       // u16 used
    u16*   sliceoff = (u16*)ws;    ws += (size_t)N_NODES * 8 * 2;   // 1.6MB
    float* dis      = (float*)ws;  ws += N_NODES * 4;
    float* selfnorm = (float*)ws;  ws += N_NODES * 4;
    int*   cnt      = (int*)ws;    ws += N_NODES * 4;
    int*   incl     = (int*)ws;    ws += N_NODES * 4;
    int*   row      = (int*)ws;    ws += N_NODES * 4;
    int*   bsum     = (int*)ws;    ws += 512 * 4;
    int*   boff     = (int*)ws;    ws += 512 * 4;
    f16*   xh       = (f16*)ws;    ws += (size_t)N_NODES * F_IN * 2;
    f16*   Wt0      = (f16*)ws;    ws += F_IN * HID * 2;
    f16*   Wt1      = (f16*)ws;    ws += HID * HID * 2;
    f16*   Wt2      = (f16*)ws;    ws += HID * NCLS * 2;
    f16*   bufA     = (f16*)ws;    ws += (size_t)N_NODES * HID * 2;
    f16*   bufB     = (f16*)ws;    ws += (size_t)N_NODES * HID * 2;

    const int nb = (N_NODES + 255) / 256;   // 391
    const int eb = (N_EDGES + 255) / 256;   // 6250

    // ---- CSR build + norm (conversions hidden under the atomic pass) ----
    k_init<<<(8 * N_NODES + 255) / 256, 256, 0, stream>>>(degp8, 8 * N_NODES);
    mega1<<<EB4 + XB + W0B + W1B + W2B, 256, 0, stream>>>(
        dst, ew, degp8, seq, x, xh, W0, Wt0, W1, Wt1, W2, Wt2);
    k_scan1<<<nb, 256, 0, stream>>>(degp8, cnt, dis, selfnorm, sliceoff, incl, bsum, N_NODES);
    k_scan2<<<1, 512, 0, stream>>>(bsum, boff, nb);
    k_scan3<<<nb, 256, 0, stream>>>(row, incl, cnt, boff, N_NODES);
    k_place<<<eb, 256, 0, stream>>>(src, dst, ew, seq, row, sliceoff, dis, csr, N_EDGES);

    const int gX = (N_NODES + 127) / 128;   // 782

    // ---- layer 1: g1 = A*X (128-wide gather), H1 = relu(g1 @ W0 + b0) ----
    agg_csr<F_IN, 16, false, false><<<(N_NODES + 15) / 16, 256, 0, stream>>>(
        xh, csr, row, cnt, selfnorm, nullptr, bufA, N_NODES);
    gemm_mfma<F_IN, HID, true><<<gX * (HID / 64), 256, 0, stream>>>(bufA, Wt0, b0, bufB, N_NODES);

    // ---- layer 2: g2 = A*H1 (256-wide gather), H2 = relu(g2 @ W1 + b1) ----
    agg_csr<HID, 32, false, false><<<(N_NODES + 7) / 8, 256, 0, stream>>>(
        bufB, csr, row, cnt, selfnorm, nullptr, bufA, N_NODES);
    gemm_mfma<HID, HID, true><<<gX * (HID / 64), 256, 0, stream>>>(bufA, Wt1, b1, bufB, N_NODES);

    // ---- layer 3: P = H2 @ W2 (no act), out = A*P + b2 (64-wide gather) ----
    gemm_mfma<HID, NCLS, false><<<gX * (NCLS / 64), 256, 0, stream>>>(bufB, Wt2, nullptr, bufA, N_NODES);
    agg_csr<NCLS, 8, true, true><<<(N_NODES + 31) / 32, 256, 0, stream>>>(
        bufA, csr, row, cnt, selfnorm, b2, outp, N_NODES);
}